// Round 5
// baseline (288.078 us; speedup 1.0000x reference)
//
#include <hip/hip_runtime.h>

// ============================ DIAGNOSTIC ROUND =============================
// PixelShuffle1d: x (8, 256, 16384) f32 -> out (8, 64, 65536) f32, upscale=4.
// out[bc*65536 + l*4 + j] = x[bc*65536 + j*16384 + l],  bc = b*64 + c'.
//
// The optimized single-pass kernel (~66 us, est.) fell below the rocprof
// top-5 cutoff (~79.5 us), so we have NO direct counters on it. This round
// trades dur_us for evidence: two dispatches, each doing 2x idempotent work
// to force them into the top-5 with full counters:
//   1) diag_copy2 : plain float4 copy x->out, 2 passes (m13 recipe) --
//      measures the achievable BW ceiling on these exact buffers.
//      Writes WRONG values; launched first.
//   2) pixel_shuffle1d_kernel : round-4 structure (LDS transpose + nt),
//      2 identical passes; launched LAST so final output is correct.
// Interpretation matrix (next round):
//   copy ~6.3 TB/s, shuffle ~3.3  -> shuffle structure at fault; dig with
//                                    VALUBusy/Occupancy/FETCH in hand.
//   copy ~3.3 too                 -> environmental limit; shuffle is at par.
//   shuffle >=5.5 TB/s sustained  -> single-pass gap is ramp/launch; fix grid.
// ===========================================================================

typedef float f32x4 __attribute__((ext_vector_type(4)));

constexpr int L = 16384;                   // input inner length
constexpr int TILE_L = 1024;               // l-positions per block tile
constexpr int TILES_PER_ROW = L / TILE_L;  // 16
constexpr int BLOCK = 256;
constexpr int QPR = L / 4;                 // float4 quads per input row
constexpr long TOTAL_QUADS = 8L * 64L * 16384L;  // 8.4M float4 quads total

// ---- Diagnostic A: plain float4 grid-stride copy, 2 passes ----------------
__global__ __launch_bounds__(256) void diag_copy2(
    const float* __restrict__ x, float* __restrict__ out) {
    const f32x4* src = reinterpret_cast<const f32x4*>(x);
    f32x4* dst = reinterpret_cast<f32x4*>(out);
    const long stride = (long)gridDim.x * blockDim.x;
#pragma unroll 1
    for (int rep = 0; rep < 2; ++rep) {
        for (long i = (long)blockIdx.x * blockDim.x + threadIdx.x;
             i < TOTAL_QUADS; i += stride) {
            dst[i] = src[i];
        }
    }
}

// ---- Diagnostic B: round-4 shuffle (LDS transpose + nt), 2 passes ---------
__global__ __launch_bounds__(256) void pixel_shuffle1d_kernel(
    const float* __restrict__ x, float* __restrict__ out) {
    __shared__ float lds[4][TILE_L];       // 16 KB

    const int t = threadIdx.x;
    const int tile = blockIdx.x & (TILES_PER_ROW - 1);
    const long bc = blockIdx.x >> 4;       // b*64 + c'
    const int l0 = tile * TILE_L;

    const f32x4* src = reinterpret_cast<const f32x4*>(x + bc * (4L * L) + l0);
    f32x4* dst = reinterpret_cast<f32x4*>(out) + (bc << 14) + l0;

#pragma unroll 1
    for (int rep = 0; rep < 2; ++rep) {
        // load phase: 4 rows x 256 quads, contiguous per instruction, nt
#pragma unroll
        for (int r = 0; r < 4; ++r) {
            f32x4 v = __builtin_nontemporal_load(&src[r * QPR + t]);
            *reinterpret_cast<f32x4*>(&lds[r][t * 4]) = v;   // ds_write_b128
        }

        __syncthreads();

        // store phase: output quad (bc*16384 + l0 + k) = column k of lds, nt
#pragma unroll
        for (int i = 0; i < 4; ++i) {
            int k = i * BLOCK + t;
            f32x4 v = {lds[0][k], lds[1][k], lds[2][k], lds[3][k]};
            __builtin_nontemporal_store(v, &dst[k]);
        }

        __syncthreads();   // protect LDS before rep 2 overwrites it
    }
}

extern "C" void kernel_launch(void* const* d_in, const int* in_sizes, int n_in,
                              void* d_out, int out_size, void* d_ws, size_t ws_size,
                              hipStream_t stream) {
    const float* x = (const float*)d_in[0];
    float* out = (float*)d_out;

    const int grid = (8 * 64) * TILES_PER_ROW;  // 8192 blocks, no tail

    // Order matters: copy writes wrong values, shuffle (last) overwrites all.
    diag_copy2<<<grid, BLOCK, 0, stream>>>(x, out);
    pixel_shuffle1d_kernel<<<grid, BLOCK, 0, stream>>>(x, out);
}

// Round 6
// 218.035 us; speedup vs baseline: 1.3212x; 1.3212x over previous
//
#include <hip/hip_runtime.h>

// PixelShuffle1d: x (8, 256, 16384) f32 -> out (8, 64, 65536) f32, upscale=4.
// out[b, c', l*4 + j] = x[b, c'*4 + j, l]
// Flattened with bc = b*64 + c':
//   out[bc*65536 + l*4 + j] = x[bc*65536 + j*16384 + l]
//
// FINAL (round-4 structure, reverted from the round-5 diagnostic).
// Roofline evidence (round-5, counter-backed, same buffers / same round):
//   - diag_copy2 (pure float4 copy, 2 passes): 88.8 us -> 44.4 us/pass,
//     6.04 TB/s app-level (96% of the 6.3 TB/s achievable copy ceiling).
//     HBM-counter rate 4.5 TB/s: mixed read+write streams + L3 absorption.
//   - this kernel x2 passes: BELOW the 87.4 us top-5 cutoff -> <43.7 us/pass,
//     i.e. the transform matches/beats the pure copy moving identical bytes.
// A reorder kernel cannot beat a pure copy; we are at the memory-system
// roofline for this op on this harness.
//
// Structure: block = 256 threads, one (bc, 1024-l) tile:
//   load : thread t nt-loads f32x4 quad t of each of 4 source rows
//          (global_load_dwordx4 nt, wave spans 1 KiB contiguous per row)
//          -> ds_write_b128 into lds[r][t*4] (conflict-free)
//   store: thread t emits output quads k = i*256+t as
//          {lds[0][k], lds[1][k], lds[2][k], lds[3][k]}
//          (4x ds_read_b32, 2 lanes/bank = free per m136)
//          -> global_store_dwordx4 nt, wave spans 1 KiB contiguous
//          (16 full 64B lines per instruction; nt avoids L3 write-allocate,
//           leaving L3 for the harness-restored, partially-resident input).

typedef float f32x4 __attribute__((ext_vector_type(4)));

constexpr int L = 16384;                   // input inner length
constexpr int TILE_L = 1024;               // l-positions per block tile
constexpr int TILES_PER_ROW = L / TILE_L;  // 16
constexpr int BLOCK = 256;
constexpr int QPR = L / 4;                 // float4 quads per input row

__global__ __launch_bounds__(256) void pixel_shuffle1d_kernel(
    const float* __restrict__ x, float* __restrict__ out) {
    __shared__ float lds[4][TILE_L];       // 16 KB

    const int t = threadIdx.x;
    const int tile = blockIdx.x & (TILES_PER_ROW - 1);
    const long bc = blockIdx.x >> 4;       // b*64 + c'
    const int l0 = tile * TILE_L;

    // ---- load phase: 4 rows x 256 quads, contiguous per instruction, nt
    const f32x4* src = reinterpret_cast<const f32x4*>(x + bc * (4L * L) + l0);
#pragma unroll
    for (int r = 0; r < 4; ++r) {
        f32x4 v = __builtin_nontemporal_load(&src[r * QPR + t]);
        *reinterpret_cast<f32x4*>(&lds[r][t * 4]) = v;     // ds_write_b128
    }

    __syncthreads();

    // ---- store phase: output quad (bc*16384 + l0 + k) = column k of lds, nt
    f32x4* dst = reinterpret_cast<f32x4*>(out) + (bc << 14) + l0;
#pragma unroll
    for (int i = 0; i < 4; ++i) {
        int k = i * BLOCK + t;
        f32x4 v = {lds[0][k], lds[1][k], lds[2][k], lds[3][k]};
        __builtin_nontemporal_store(v, &dst[k]);
    }
}

extern "C" void kernel_launch(void* const* d_in, const int* in_sizes, int n_in,
                              void* d_out, int out_size, void* d_ws, size_t ws_size,
                              hipStream_t stream) {
    const float* x = (const float*)d_in[0];
    float* out = (float*)d_out;

    const int grid = (8 * 64) * TILES_PER_ROW;  // 8192 blocks, no tail
    pixel_shuffle1d_kernel<<<grid, BLOCK, 0, stream>>>(x, out);
}